// Round 4
// baseline (773.916 us; speedup 1.0000x reference)
//
#include <hip/hip_runtime.h>
#include <stdint.h>

#define NB 64
#define NS 2048
#define ND 1024
#define NU 1024

typedef __attribute__((ext_vector_type(8))) _Float16 f16x8;
typedef __attribute__((ext_vector_type(4))) float f32x4;

// async global->LDS, 16B per lane; lds base must be wave-uniform (HW: base + lane*16)
__device__ __forceinline__ void gload_lds16(const void* g, void* l) {
    __builtin_amdgcn_global_load_lds(
        (const __attribute__((address_space(1))) unsigned int*)g,
        (__attribute__((address_space(3))) unsigned int*)l, 16, 0, 0);
}

// ---------------- K1: U [d][u] fp32 -> Ut [u][d] f16 ----------------
__global__ void transpose_u(const float* __restrict__ Uk, _Float16* __restrict__ Ut) {
    __shared__ float tile[64][65];
    int d0 = blockIdx.x * 64, u0 = blockIdx.y * 64;
    int tid = threadIdx.x;
    #pragma unroll
    for (int i = 0; i < 16; ++i) {
        int idx = i * 256 + tid;
        int r = idx >> 6, c = idx & 63;
        tile[r][c] = Uk[(size_t)(d0 + r) * NU + (u0 + c)];
    }
    __syncthreads();
    #pragma unroll
    for (int i = 0; i < 16; ++i) {
        int idx = i * 256 + tid;
        int c = idx >> 6, r = idx & 63;
        Ut[(size_t)(u0 + c) * ND + (d0 + r)] = (_Float16)tile[r][c];
    }
}

// ---------------- K2: off[b][u] = s_prev@W + W_bias + U_bias ----------------
__global__ void prep_off(const float* __restrict__ s_prev, const float* __restrict__ Wk,
                         const float* __restrict__ Wb, const float* __restrict__ Ub,
                         float* __restrict__ off) {
    int blk = blockIdx.x;
    int b = blk >> 2, ut = blk & 3;
    int tid = threadIdx.x;
    int u = ut * 256 + tid;
    __shared__ float sp[ND];
    #pragma unroll
    for (int i = tid; i < ND; i += 256) sp[i] = s_prev[(size_t)b * ND + i];
    __syncthreads();
    float acc = 0.f;
    #pragma unroll 8
    for (int d = 0; d < ND; ++d) acc += sp[d] * Wk[(size_t)d * NU + u];
    off[(size_t)b * NU + u] = acc + Wb[u] + Ub[u];
}

// ---------------- K3: fused scores GEMM, 2-phase LDS double-buffer ----------------
// scores[b][s] += sum_u tanh(off[b][u] + sum_d h[b][s][d]*U[d][u]) * V[u]
// 128x128 tile, BK=32, 4 waves (2x2), each wave 64x64 = 4x4 frags of 16x16x32 f16 MFMA.
// Both operands staged via global_load_lds (pre-swizzled global source, linear dest):
//   As32 fp32 [128][32], 8x16B slots/row, involution slot^(row&7)  (2 lanes/bank on read = free)
//   Bs   f16  [128][32], 4x16B slots/row, involution slot^((row>>1)&3)  (0-conflict, R1-measured)
// Schedule: STAGE(next->buf^1) issued BEFORE COMPUTE(cur->buf); single __syncthreads per
// K-step drains vmcnt AFTER the compute phase -> global latency hidden (T3 minimum 2-phase).
__launch_bounds__(256, 2)
__global__ void scores_kernel(const float* __restrict__ h,
                              const _Float16* __restrict__ Ut,   // [NU][ND]
                              const float* __restrict__ off,     // [NB][NU]
                              const float* __restrict__ V,       // [NU]
                              float* __restrict__ scores)        // [NB][NS], pre-zeroed
{
    // XCD-bijective swizzle: keep the 8 u-blocks of one h-slab on one XCD
    int hw = blockIdx.x;
    int chunk = gridDim.x >> 3;                    // 8192/8 = 1024
    int logical = (hw & 7) * chunk + (hw >> 3);
    int ublk = logical & 7;
    int t2 = logical >> 3;
    int sblk = t2 & 15;
    int b = t2 >> 4;
    int s0 = sblk * 128, u0 = ublk * 128;

    __shared__ float As32[2][128][32];    // 2 x 16 KB, swizzled fp32 h tiles
    __shared__ _Float16 Bs[2][128][32];   // 2 x 8 KB, swizzled f16 U^T tiles

    int tid = threadIdx.x;
    int w = tid >> 6, l = tid & 63;
    int wr = w >> 1, wc = w & 1;
    int rg = l >> 4, cl = l & 15;

    f32x4 acc[4][4] = {};

    const float* hA = h + ((size_t)b * NS + s0) * ND;

    // A staging: wave w stages rows w*32..w*32+31, 4 issues of 8 rows each.
    // LDS phys slot (l&7) receives global slot (l&7)^(row&7)  (involution, full 8-slot span).
    const float* srcA[4];
    #pragma unroll
    for (int i = 0; i < 4; ++i) {
        int row = w * 32 + i * 8 + (l >> 3);
        int gslot = (l & 7) ^ (row & 7);
        srcA[i] = hA + (size_t)row * ND + gslot * 4;
    }
    // B staging: wave w stages rows w*32..w*32+31, 2 issues of 16 rows each.
    const _Float16* srcB[2];
    #pragma unroll
    for (int i = 0; i < 2; ++i) {
        int row = w * 32 + i * 16 + (l >> 2);
        srcB[i] = Ut + (size_t)(u0 + row) * ND + (((l & 3) ^ ((row >> 1) & 3)) * 8);
    }

    #define STAGE(BUF, KK) { \
        _Pragma("unroll") \
        for (int i = 0; i < 4; ++i) \
            gload_lds16((const void*)(srcA[i] + (KK) * 32), (void*)&As32[BUF][w * 32 + i * 8][0]); \
        _Pragma("unroll") \
        for (int i = 0; i < 2; ++i) \
            gload_lds16((const void*)(srcB[i] + (KK) * 32), (void*)&Bs[BUF][w * 32 + i * 16][0]); \
    }

    #define COMPUTE(BUF) { \
        f16x8 af[4], bf[4]; \
        _Pragma("unroll") \
        for (int m = 0; m < 4; ++m) { \
            int r_ = wr * 64 + m * 16 + cl; \
            int msk_ = r_ & 7; \
            int p0 = (((rg << 1) ^ msk_)) * 4; \
            int p1 = ((((rg << 1) | 1) ^ msk_)) * 4; \
            f32x4 lo = *(const f32x4*)&As32[BUF][r_][p0]; \
            f32x4 hi = *(const f32x4*)&As32[BUF][r_][p1]; \
            f16x8 a; \
            a[0] = (_Float16)lo[0]; a[1] = (_Float16)lo[1]; \
            a[2] = (_Float16)lo[2]; a[3] = (_Float16)lo[3]; \
            a[4] = (_Float16)hi[0]; a[5] = (_Float16)hi[1]; \
            a[6] = (_Float16)hi[2]; a[7] = (_Float16)hi[3]; \
            af[m] = a; \
        } \
        _Pragma("unroll") \
        for (int n = 0; n < 4; ++n) { \
            int r_ = wc * 64 + n * 16 + cl; \
            bf[n] = *(const f16x8*)&Bs[BUF][r_][(rg ^ ((r_ >> 1) & 3)) * 8]; \
        } \
        _Pragma("unroll") \
        for (int m = 0; m < 4; ++m) \
            _Pragma("unroll") \
            for (int n = 0; n < 4; ++n) \
                acc[m][n] = __builtin_amdgcn_mfma_f32_16x16x32_f16(af[m], bf[n], acc[m][n], 0, 0, 0); \
    }

    // prologue: stage tile 0 into buffer 0
    STAGE(0, 0);
    __syncthreads();

    for (int kk = 0; kk < 31; ++kk) {
        STAGE((kk + 1) & 1, kk + 1);   // issue next tile's loads first
        COMPUTE(kk & 1);               // compute current while loads fly
        __syncthreads();               // one drain+barrier per K-step
    }
    COMPUTE(1);                        // tile 31 (31&1 == 1), no further staging

    #undef STAGE
    #undef COMPUTE

    // epilogue: tanh(acc + off)*V, reduce over this wave's 64 u's, atomic into scores
    float offv[4], vv[4];
    #pragma unroll
    for (int n = 0; n < 4; ++n) {
        int u = u0 + wc * 64 + n * 16 + cl;
        offv[n] = off[(size_t)b * NU + u];
        vv[n] = V[u];
    }
    #pragma unroll
    for (int m = 0; m < 4; ++m) {
        #pragma unroll
        for (int i = 0; i < 4; ++i) {
            float sacc = 0.f;
            #pragma unroll
            for (int n = 0; n < 4; ++n) {
                float x = acc[m][n][i] + offv[n];
                float t = 1.0f - 2.0f / (1.0f + __expf(2.0f * x));  // tanh(x)
                sacc += t * vv[n];
            }
            #pragma unroll
            for (int msk = 1; msk < 16; msk <<= 1) sacc += __shfl_xor(sacc, msk, 64);
            if (cl == 0)
                atomicAdd(&scores[(size_t)b * NS + s0 + wr * 64 + m * 16 + rg * 4 + i], sacc);
        }
    }
}

// ---------------- K4: softmax over S per batch ----------------
__global__ void softmax_kernel(const float* __restrict__ scores, float* __restrict__ outw) {
    int b = blockIdx.x, tid = threadIdx.x;
    const float* src = scores + (size_t)b * NS;
    float4 x0 = *(const float4*)(src + tid * 8);
    float4 x1 = *(const float4*)(src + tid * 8 + 4);
    float m = fmaxf(fmaxf(fmaxf(x0.x, x0.y), fmaxf(x0.z, x0.w)),
                    fmaxf(fmaxf(x1.x, x1.y), fmaxf(x1.z, x1.w)));
    #pragma unroll
    for (int msk = 1; msk < 64; msk <<= 1) m = fmaxf(m, __shfl_xor(m, msk, 64));
    __shared__ float redm[4], reds[4];
    if ((tid & 63) == 0) redm[tid >> 6] = m;
    __syncthreads();
    m = fmaxf(fmaxf(redm[0], redm[1]), fmaxf(redm[2], redm[3]));
    float e[8];
    e[0] = __expf(x0.x - m); e[1] = __expf(x0.y - m); e[2] = __expf(x0.z - m); e[3] = __expf(x0.w - m);
    e[4] = __expf(x1.x - m); e[5] = __expf(x1.y - m); e[6] = __expf(x1.z - m); e[7] = __expf(x1.w - m);
    float s = e[0] + e[1] + e[2] + e[3] + e[4] + e[5] + e[6] + e[7];
    #pragma unroll
    for (int msk = 1; msk < 64; msk <<= 1) s += __shfl_xor(s, msk, 64);
    if ((tid & 63) == 0) reds[tid >> 6] = s;
    __syncthreads();
    float Z = reds[0] + reds[1] + reds[2] + reds[3];
    float r = 1.0f / Z;
    float4 o0 = { e[0] * r, e[1] * r, e[2] * r, e[3] * r };
    float4 o1 = { e[4] * r, e[5] * r, e[6] * r, e[7] * r };
    *(float4*)(outw + (size_t)b * NS + tid * 8) = o0;
    *(float4*)(outw + (size_t)b * NS + tid * 8 + 4) = o1;
}

// ---------------- K5: context partials over s-chunks ----------------
__global__ void context_partial(const float* __restrict__ h, const float* __restrict__ wgt,
                                float* __restrict__ part) {
    int sc = blockIdx.x, b = blockIdx.y, tid = threadIdx.x;   // 16 chunks x 128 s
    __shared__ float lw[128];
    if (tid < 128) lw[tid] = wgt[(size_t)b * NS + sc * 128 + tid];
    __syncthreads();
    const float* hb = h + ((size_t)b * NS + sc * 128) * ND + tid * 4;
    float4 acc = { 0.f, 0.f, 0.f, 0.f };
    #pragma unroll 4
    for (int s = 0; s < 128; ++s) {
        float4 hv = *(const float4*)(hb + (size_t)s * ND);
        float wv = lw[s];
        acc.x += hv.x * wv; acc.y += hv.y * wv; acc.z += hv.z * wv; acc.w += hv.w * wv;
    }
    *(float4*)(part + ((size_t)(sc * NB + b)) * ND + tid * 4) = acc;
}

// ---------------- K6: reduce partials -> context ----------------
__global__ void context_reduce(const float* __restrict__ part, float* __restrict__ outc) {
    int b = blockIdx.x, tid = threadIdx.x;
    float4 acc = { 0.f, 0.f, 0.f, 0.f };
    #pragma unroll
    for (int k = 0; k < 16; ++k) {
        float4 p = *(const float4*)(part + ((size_t)(k * NB + b)) * ND + tid * 4);
        acc.x += p.x; acc.y += p.y; acc.z += p.z; acc.w += p.w;
    }
    *(float4*)(outc + (size_t)b * ND + tid * 4) = acc;
}

extern "C" void kernel_launch(void* const* d_in, const int* in_sizes, int n_in,
                              void* d_out, int out_size, void* d_ws, size_t ws_size,
                              hipStream_t stream) {
    const float* s_prev = (const float*)d_in[0];
    const float* hidden = (const float*)d_in[1];
    const float* Wk     = (const float*)d_in[2];
    const float* Wb     = (const float*)d_in[3];
    const float* Uk     = (const float*)d_in[4];
    const float* Ub     = (const float*)d_in[5];
    const float* Vk     = (const float*)d_in[6];
    // V_bias (d_in[7]) is a uniform score shift -> softmax-invariant, dropped.

    float* out_ctx = (float*)d_out;            // [64][1024]
    float* out_w   = out_ctx + NB * ND;        // [64][2048]

    char* ws = (char*)d_ws;
    _Float16* Ut  = (_Float16*)ws;                                   // 2 MB
    float* off    = (float*)(ws + (size_t)(2 << 20));                // 256 KB
    float* scores = (float*)(ws + (size_t)(2 << 20) + (256 << 10));  // 512 KB
    float* part   = (float*)(ws + (size_t)(2 << 20) + (768 << 10));  // 4 MB

    hipMemsetAsync(scores, 0, (size_t)NB * NS * sizeof(float), stream);
    transpose_u<<<dim3(16, 16), 256, 0, stream>>>(Uk, Ut);
    prep_off<<<256, 256, 0, stream>>>(s_prev, Wk, Wb, Ub, off);
    scores_kernel<<<8192, 256, 0, stream>>>(hidden, Ut, off, Vk, scores);
    softmax_kernel<<<NB, 256, 0, stream>>>(scores, out_w);
    context_partial<<<dim3(16, NB), 256, 0, stream>>>(hidden, out_w, part);
    context_reduce<<<NB, 256, 0, stream>>>(part, out_ctx);
}

// Round 5
// 578.088 us; speedup vs baseline: 1.3387x; 1.3387x over previous
//
#include <hip/hip_runtime.h>
#include <stdint.h>

#define NB 64
#define NS 2048
#define ND 1024
#define NU 1024

typedef __attribute__((ext_vector_type(8))) _Float16 f16x8;
typedef __attribute__((ext_vector_type(4))) float f32x4;

// async global->LDS, 16B per lane; lds base must be wave-uniform (HW: base + lane*16)
__device__ __forceinline__ void gload_lds16(const void* g, void* l) {
    __builtin_amdgcn_global_load_lds(
        (const __attribute__((address_space(1))) unsigned int*)g,
        (__attribute__((address_space(3))) unsigned int*)l, 16, 0, 0);
}

// ---------------- K1: U [d][u] fp32 -> Ut [u][d] f16 ----------------
__global__ void transpose_u(const float* __restrict__ Uk, _Float16* __restrict__ Ut) {
    __shared__ float tile[64][65];
    int d0 = blockIdx.x * 64, u0 = blockIdx.y * 64;
    int tid = threadIdx.x;
    #pragma unroll
    for (int i = 0; i < 16; ++i) {
        int idx = i * 256 + tid;
        int r = idx >> 6, c = idx & 63;
        tile[r][c] = Uk[(size_t)(d0 + r) * NU + (u0 + c)];
    }
    __syncthreads();
    #pragma unroll
    for (int i = 0; i < 16; ++i) {
        int idx = i * 256 + tid;
        int c = idx >> 6, r = idx & 63;
        Ut[(size_t)(u0 + c) * ND + (d0 + r)] = (_Float16)tile[r][c];
    }
}

// ---------------- K2: off[b][u] = s_prev@W + W_bias + U_bias ----------------
__global__ void prep_off(const float* __restrict__ s_prev, const float* __restrict__ Wk,
                         const float* __restrict__ Wb, const float* __restrict__ Ub,
                         float* __restrict__ off) {
    int blk = blockIdx.x;
    int b = blk >> 2, ut = blk & 3;
    int tid = threadIdx.x;
    int u = ut * 256 + tid;
    __shared__ float sp[ND];
    #pragma unroll
    for (int i = tid; i < ND; i += 256) sp[i] = s_prev[(size_t)b * ND + i];
    __syncthreads();
    float acc = 0.f;
    #pragma unroll 8
    for (int d = 0; d < ND; ++d) acc += sp[d] * Wk[(size_t)d * NU + u];
    off[(size_t)b * NU + u] = acc + Wb[u] + Ub[u];
}

// ---------------- K3: fused scores GEMM, counted-vmcnt pipeline ----------------
// scores[b][s] += sum_u tanh(off[b][u] + sum_d h[b][s][d]*U[d][u]) * V[u]
// 128x128 tile, BK=32, 4 waves (2x2), each wave 64x64 = 4x4 frags of 16x16x32 f16 MFMA.
// Tiles: f16 [128][32] (64B rows, 4x16B slots), involution slot^((row>>1)&3) on BOTH
// write and read sides -- the R1-measured ZERO-conflict geometry.
//   As[2]: A regs (fp32 global) -> cvt f16 -> swizzled ds_write; double-buffered.
//   Bs[3]: global_load_lds, pre-swizzled GLOBAL source, linear dest; triple-buffered
//          (DMA write at step t can race a 2-buffer reader; 3 buffers + 1 barrier = safe).
// Schedule per K-step (ONE raw s_barrier, counted vmcnt -- loads stay in flight):
//   vmcnt(2)  -> A(t) regs ready          (B(t) still flying)
//   CVT+ds_write A(t) -> As[t&1]
//   issue A(t+1) loads, issue B(t+1) gload_lds
//   vmcnt(6) lgkmcnt(0) -> B(t) landed, my ds_writes done   (A(t+1)+B(t+1) stay in flight)
//   s_barrier -> COMPUTE(As[t&1], Bs[t%3])
__launch_bounds__(256, 4)
__global__ void scores_kernel(const float* __restrict__ h,
                              const _Float16* __restrict__ Ut,   // [NU][ND]
                              const float* __restrict__ off,     // [NB][NU]
                              const float* __restrict__ V,       // [NU]
                              float* __restrict__ scores)        // [NB][NS], pre-zeroed
{
    // XCD-bijective swizzle: keep the 8 u-blocks of one h-slab on one XCD
    int hw = blockIdx.x;
    int chunk = gridDim.x >> 3;                    // 8192/8 = 1024
    int logical = (hw & 7) * chunk + (hw >> 3);
    int ublk = logical & 7;
    int t2 = logical >> 3;
    int sblk = t2 & 15;
    int b = t2 >> 4;
    int s0 = sblk * 128, u0 = ublk * 128;

    __shared__ _Float16 As[2][128][32];   // 16 KB, swizzled f16 h tiles
    __shared__ _Float16 Bs[3][128][32];   // 24 KB, swizzled f16 U^T tiles

    int tid = threadIdx.x;
    int w = tid >> 6, l = tid & 63;
    int wr = w >> 1, wc = w & 1;
    int rg = l >> 4, cl = l & 15;

    f32x4 acc[4][4] = {};

    const float* hA = h + ((size_t)b * NS + s0) * ND;

    // A-load geometry: lane covers row p*32+(tid>>3), 16B at k-offset (tid&7)*4 floats
    int arow = tid >> 3;              // 0..31
    int acol4 = (tid & 7) * 4;
    // A-write geometry: logical 16B slot aslog, 8B half ahalf
    int aslog = (tid & 7) >> 1;
    int ahalf = tid & 1;
    // B staging: wave w stages rows w*32..w*32+31, 2 issues of 16 rows; global pre-swizzled
    const _Float16* srcB[2];
    #pragma unroll
    for (int i = 0; i < 2; ++i) {
        int row = w * 32 + i * 16 + (l >> 2);
        srcB[i] = Ut + (size_t)(u0 + row) * ND + (((l & 3) ^ ((row >> 1) & 3)) * 8);
    }

    float4 av[4];

    #define LOADA(KK) { \
        _Pragma("unroll") \
        for (int p = 0; p < 4; ++p) \
            av[p] = *(const float4*)(hA + (size_t)(p * 32 + arow) * ND + (KK) * 32 + acol4); \
    }

    #define ISSUEB(BI, KK) { \
        _Pragma("unroll") \
        for (int i = 0; i < 2; ++i) \
            gload_lds16((const void*)(srcB[i] + (KK) * 32), (void*)&Bs[BI][w * 32 + i * 16][0]); \
    }

    #define CVTW(ABUF) { \
        _Pragma("unroll") \
        for (int p = 0; p < 4; ++p) { \
            int r_ = p * 32 + arow; \
            int sp_ = aslog ^ ((r_ >> 1) & 3); \
            union { _Float16 e[4]; uint2 u2; } cv; \
            cv.e[0] = (_Float16)av[p].x; cv.e[1] = (_Float16)av[p].y; \
            cv.e[2] = (_Float16)av[p].z; cv.e[3] = (_Float16)av[p].w; \
            *(uint2*)&As[ABUF][r_][sp_ * 8 + ahalf * 4] = cv.u2; \
        } \
    }

    #define COMPUTE(ABUF, BI) { \
        f16x8 af[4], bf[4]; \
        _Pragma("unroll") \
        for (int m = 0; m < 4; ++m) { \
            int r_ = wr * 64 + m * 16 + cl; \
            af[m] = *(const f16x8*)&As[ABUF][r_][(rg ^ ((r_ >> 1) & 3)) * 8]; \
        } \
        _Pragma("unroll") \
        for (int n = 0; n < 4; ++n) { \
            int r_ = wc * 64 + n * 16 + cl; \
            bf[n] = *(const f16x8*)&Bs[BI][r_][(rg ^ ((r_ >> 1) & 3)) * 8]; \
        } \
        _Pragma("unroll") \
        for (int m = 0; m < 4; ++m) \
            _Pragma("unroll") \
            for (int n = 0; n < 4; ++n) \
                acc[m][n] = __builtin_amdgcn_mfma_f32_16x16x32_f16(af[m], bf[n], acc[m][n], 0, 0, 0); \
    }

    // prologue: A(0) -> regs, B(0) -> Bs[0]
    LOADA(0);
    ISSUEB(0, 0);

    int bcur = 0;
    for (int t = 0; t < 31; ++t) {
        asm volatile("s_waitcnt vmcnt(2)" ::: "memory");    // A(t) ready; B(t) flying
        __builtin_amdgcn_sched_barrier(0);
        CVTW(t & 1);
        LOADA(t + 1);
        int bnxt = bcur + 1; if (bnxt == 3) bnxt = 0;
        ISSUEB(bnxt, t + 1);
        asm volatile("s_waitcnt vmcnt(6) lgkmcnt(0)" ::: "memory");  // B(t)+my ds_writes done
        __builtin_amdgcn_sched_barrier(0);
        __builtin_amdgcn_s_barrier();
        __builtin_amdgcn_sched_barrier(0);
        COMPUTE(t & 1, bcur);
        bcur = bnxt;
    }
    // t = 31 (no further staging)
    asm volatile("s_waitcnt vmcnt(0)" ::: "memory");
    __builtin_amdgcn_sched_barrier(0);
    CVTW(1);
    asm volatile("s_waitcnt lgkmcnt(0)" ::: "memory");
    __builtin_amdgcn_sched_barrier(0);
    __builtin_amdgcn_s_barrier();
    __builtin_amdgcn_sched_barrier(0);
    COMPUTE(1, bcur);

    #undef LOADA
    #undef ISSUEB
    #undef CVTW
    #undef COMPUTE

    // epilogue: tanh(acc + off)*V, reduce over this wave's 64 u's, atomic into scores
    float offv[4], vv[4];
    #pragma unroll
    for (int n = 0; n < 4; ++n) {
        int u = u0 + wc * 64 + n * 16 + cl;
        offv[n] = off[(size_t)b * NU + u];
        vv[n] = V[u];
    }
    #pragma unroll
    for (int m = 0; m < 4; ++m) {
        #pragma unroll
        for (int i = 0; i < 4; ++i) {
            float sacc = 0.f;
            #pragma unroll
            for (int n = 0; n < 4; ++n) {
                float x = acc[m][n][i] + offv[n];
                float t = 1.0f - 2.0f / (1.0f + __expf(2.0f * x));  // tanh(x)
                sacc += t * vv[n];
            }
            #pragma unroll
            for (int msk = 1; msk < 16; msk <<= 1) sacc += __shfl_xor(sacc, msk, 64);
            if (cl == 0)
                atomicAdd(&scores[(size_t)b * NS + s0 + wr * 64 + m * 16 + rg * 4 + i], sacc);
        }
    }
}

// ---------------- K4: softmax over S per batch ----------------
__global__ void softmax_kernel(const float* __restrict__ scores, float* __restrict__ outw) {
    int b = blockIdx.x, tid = threadIdx.x;
    const float* src = scores + (size_t)b * NS;
    float4 x0 = *(const float4*)(src + tid * 8);
    float4 x1 = *(const float4*)(src + tid * 8 + 4);
    float m = fmaxf(fmaxf(fmaxf(x0.x, x0.y), fmaxf(x0.z, x0.w)),
                    fmaxf(fmaxf(x1.x, x1.y), fmaxf(x1.z, x1.w)));
    #pragma unroll
    for (int msk = 1; msk < 64; msk <<= 1) m = fmaxf(m, __shfl_xor(m, msk, 64));
    __shared__ float redm[4], reds[4];
    if ((tid & 63) == 0) redm[tid >> 6] = m;
    __syncthreads();
    m = fmaxf(fmaxf(redm[0], redm[1]), fmaxf(redm[2], redm[3]));
    float e[8];
    e[0] = __expf(x0.x - m); e[1] = __expf(x0.y - m); e[2] = __expf(x0.z - m); e[3] = __expf(x0.w - m);
    e[4] = __expf(x1.x - m); e[5] = __expf(x1.y - m); e[6] = __expf(x1.z - m); e[7] = __expf(x1.w - m);
    float s = e[0] + e[1] + e[2] + e[3] + e[4] + e[5] + e[6] + e[7];
    #pragma unroll
    for (int msk = 1; msk < 64; msk <<= 1) s += __shfl_xor(s, msk, 64);
    if ((tid & 63) == 0) reds[tid >> 6] = s;
    __syncthreads();
    float Z = reds[0] + reds[1] + reds[2] + reds[3];
    float r = 1.0f / Z;
    float4 o0 = { e[0] * r, e[1] * r, e[2] * r, e[3] * r };
    float4 o1 = { e[4] * r, e[5] * r, e[6] * r, e[7] * r };
    *(float4*)(outw + (size_t)b * NS + tid * 8) = o0;
    *(float4*)(outw + (size_t)b * NS + tid * 8 + 4) = o1;
}

// ---------------- K5: context partials over s-chunks ----------------
__global__ void context_partial(const float* __restrict__ h, const float* __restrict__ wgt,
                                float* __restrict__ part) {
    int sc = blockIdx.x, b = blockIdx.y, tid = threadIdx.x;   // 16 chunks x 128 s
    __shared__ float lw[128];
    if (tid < 128) lw[tid] = wgt[(size_t)b * NS + sc * 128 + tid];
    __syncthreads();
    const float* hb = h + ((size_t)b * NS + sc * 128) * ND + tid * 4;
    float4 acc = { 0.f, 0.f, 0.f, 0.f };
    #pragma unroll 4
    for (int s = 0; s < 128; ++s) {
        float4 hv = *(const float4*)(hb + (size_t)s * ND);
        float wv = lw[s];
        acc.x += hv.x * wv; acc.y += hv.y * wv; acc.z += hv.z * wv; acc.w += hv.w * wv;
    }
    *(float4*)(part + ((size_t)(sc * NB + b)) * ND + tid * 4) = acc;
}

// ---------------- K6: reduce partials -> context ----------------
__global__ void context_reduce(const float* __restrict__ part, float* __restrict__ outc) {
    int b = blockIdx.x, tid = threadIdx.x;
    float4 acc = { 0.f, 0.f, 0.f, 0.f };
    #pragma unroll
    for (int k = 0; k < 16; ++k) {
        float4 p = *(const float4*)(part + ((size_t)(k * NB + b)) * ND + tid * 4);
        acc.x += p.x; acc.y += p.y; acc.z += p.z; acc.w += p.w;
    }
    *(float4*)(outc + (size_t)b * ND + tid * 4) = acc;
}

extern "C" void kernel_launch(void* const* d_in, const int* in_sizes, int n_in,
                              void* d_out, int out_size, void* d_ws, size_t ws_size,
                              hipStream_t stream) {
    const float* s_prev = (const float*)d_in[0];
    const float* hidden = (const float*)d_in[1];
    const float* Wk     = (const float*)d_in[2];
    const float* Wb     = (const float*)d_in[3];
    const float* Uk     = (const float*)d_in[4];
    const float* Ub     = (const float*)d_in[5];
    const float* Vk     = (const float*)d_in[6];
    // V_bias (d_in[7]) is a uniform score shift -> softmax-invariant, dropped.

    float* out_ctx = (float*)d_out;            // [64][1024]
    float* out_w   = out_ctx + NB * ND;        // [64][2048]

    char* ws = (char*)d_ws;
    _Float16* Ut  = (_Float16*)ws;                                   // 2 MB
    float* off    = (float*)(ws + (size_t)(2 << 20));                // 256 KB
    float* scores = (float*)(ws + (size_t)(2 << 20) + (256 << 10));  // 512 KB
    float* part   = (float*)(ws + (size_t)(2 << 20) + (768 << 10));  // 4 MB

    hipMemsetAsync(scores, 0, (size_t)NB * NS * sizeof(float), stream);
    transpose_u<<<dim3(16, 16), 256, 0, stream>>>(Uk, Ut);
    prep_off<<<256, 256, 0, stream>>>(s_prev, Wk, Wb, Ub, off);
    scores_kernel<<<8192, 256, 0, stream>>>(hidden, Ut, off, Vk, scores);
    softmax_kernel<<<NB, 256, 0, stream>>>(scores, out_w);
    context_partial<<<dim3(16, NB), 256, 0, stream>>>(hidden, out_w, part);
    context_reduce<<<NB, 256, 0, stream>>>(part, out_ctx);
}